// Round 7
// baseline (2709.931 us; speedup 1.0000x reference)
//
#include <hip/hip_runtime.h>
#include <math.h>

// Problem: B=64, R=20, L=1024, D=2048 fp32.  out[b,l] = max_r <region[b,r,:], word[b,l,:]>
// Memory-bound: 548 MB mandatory -> ~84us @ 6.6TB/s measured-achievable.
//
// Round-7 structure: BARRIER-FREE main loop.
//  - Regions for one batch = 20*2048*4B = 160 KB = exactly one CU's LDS.
//    Stage ALL of it once (global_load_lds, layout [chunk][region][256]),
//    one __syncthreads, then LDS is read-only: no barriers, no vmcnt(0)
//    drains in the main loop (rounds 2-6 all paid a full pipeline drain
//    per chunk - the dominant cost).
//  - 512 threads = 8 waves, 1 block/CU (LDS-capped). Each wave: 4 words
//    per tile, 4 tiles per block (128 words/block, each word read once).
//  - words double-buffered in registers (wvA/wvB, statically indexed via
//    fully-unrolled chunk loop) -> FMA loop never waits on VMEM.
//  - no min-waves launch bound (rounds 3/4: VGPR caps spill the 80-reg acc;
//    occupancy here is LDS-capped anyway, VGPR has headroom to 256).
#define NREG  20
#define LWORDS 1024
#define DDIM  2048
#define TPB   512
#define NWAVE 8
#define WPW   4                     // words per wave per tile
#define WPT   (NWAVE * WPW)         // 32 words per tile
#define TILES 4
#define WPB   (WPT * TILES)         // 128 words per block
#define DK    256                   // floats per chunk (64 lanes x float4)
#define NCHUNK (DDIM / DK)          // 8
#define NLTILE (NREG * NCHUNK)      // 160 1KB lds tiles

// async global->LDS, 16B per lane; dst must be wave-uniform (HW adds lane*16)
__device__ __forceinline__ void gload_lds16(const float* src, float* dst) {
    __builtin_amdgcn_global_load_lds(
        (const __attribute__((address_space(1))) void*)src,
        (__attribute__((address_space(3))) void*)dst,
        16, 0, 0);
}

// DPP full-wave (64-lane) sum; result valid in lane 63.
template <int CTRL>
__device__ __forceinline__ float dpp_add_f32(float v) {
    int s = __builtin_amdgcn_update_dpp(0, __float_as_int(v), CTRL, 0xf, 0xf, true);
    return v + __int_as_float(s);
}
__device__ __forceinline__ float wave_sum64(float v) {
    v = dpp_add_f32<0x111>(v);  // row_shr:1
    v = dpp_add_f32<0x112>(v);  // row_shr:2
    v = dpp_add_f32<0x114>(v);  // row_shr:4
    v = dpp_add_f32<0x118>(v);  // row_shr:8
    v = dpp_add_f32<0x142>(v);  // row_bcast:15
    v = dpp_add_f32<0x143>(v);  // row_bcast:31 -> lane 63 = total
    return v;
}

__global__ __launch_bounds__(TPB)
void score_max_kernel(const float* __restrict__ in0,   // (B*20, D) regions
                      const float* __restrict__ in1,   // (B, L, D) words
                      float* __restrict__ out) {       // (B, 1, L)
    __shared__ float lds[NCHUNK][NREG][DK];            // 160 KB = full CU LDS

    const int bid  = blockIdx.x;
    // bid = tb*64 + b: batch b always lands on XCD (b%8) -> regions L2-resident.
    const int b    = bid & 63;
    const int tb   = bid >> 6;                          // 0..7 (128-word slabs)
    const int tid  = threadIdx.x;
    const int wave = tid >> 6;
    const int lane = tid & 63;

    const float* regbase = in0 + (size_t)b * NREG * DDIM;

    // ---- stage ALL regions into LDS once, layout [chunk][region][DK] ----
    #pragma unroll
    for (int i = 0; i < NLTILE / NWAVE; ++i) {          // 20 stage insts/thread
        const int t = i * NWAVE + wave;                  // 1KB tile id (wave-uniform)
        const int c = t / NREG;
        const int r = t % NREG;
        gload_lds16(regbase + (size_t)r * DDIM + c * DK + lane * 4,
                    &lds[c][r][0]);
    }

    auto wvload = [&](float4* wv, int tile, int c) {
        const float* p = in1 + ((size_t)b * LWORDS + tb * WPB + tile * WPT + wave * WPW) * DDIM
                             + c * DK + lane * 4;
        #pragma unroll
        for (int w = 0; w < WPW; ++w)
            wv[w] = *reinterpret_cast<const float4*>(p + (size_t)w * DDIM);
    };

    float4 wvA[WPW], wvB[WPW];
    wvload(wvA, 0, 0);
    __syncthreads();   // the ONLY barrier: drains stage (vmcnt 0) + wvA

    for (int tile = 0; tile < TILES; ++tile) {
        float acc[NREG][WPW];
        #pragma unroll
        for (int r = 0; r < NREG; ++r)
            #pragma unroll
            for (int w = 0; w < WPW; ++w) acc[r][w] = 0.0f;

        #pragma unroll
        for (int c = 0; c < NCHUNK; ++c) {
            // static ping-pong: c is compile-time under full unroll
            float4* cur = (c & 1) ? wvB : wvA;
            float4* nxt = (c & 1) ? wvA : wvB;
            if (c + 1 < NCHUNK)         wvload(nxt, tile, c + 1);      // prefetch
            else if (tile + 1 < TILES)  wvload(nxt, tile + 1, 0);      // cross-tile

            #pragma unroll
            for (int r = 0; r < NREG; ++r) {
                const float4 rv = *reinterpret_cast<const float4*>(&lds[c][r][lane * 4]);
                #pragma unroll
                for (int w = 0; w < WPW; ++w) {
                    float a = acc[r][w];
                    a = fmaf(rv.x, cur[w].x, a);
                    a = fmaf(rv.y, cur[w].y, a);
                    a = fmaf(rv.z, cur[w].z, a);
                    a = fmaf(rv.w, cur[w].w, a);
                    acc[r][w] = a;
                }
            }
        }

        // epilogue: DPP wave-sum each acc, max over regions, lane 63 stores.
        #pragma unroll
        for (int w = 0; w < WPW; ++w) {
            float m = -INFINITY;
            #pragma unroll
            for (int r = 0; r < NREG; ++r)
                m = fmaxf(m, wave_sum64(acc[r][w]));
            if (lane == 63)
                out[(size_t)b * LWORDS + tb * WPB + tile * WPT + wave * WPW + w] = m;
        }
    }
}

extern "C" void kernel_launch(void* const* d_in, const int* in_sizes, int n_in,
                              void* d_out, int out_size, void* d_ws, size_t ws_size,
                              hipStream_t stream) {
    const float* in0 = (const float*)d_in[0];   // (B*20, D)
    const float* in1 = (const float*)d_in[1];   // (B, L, D)
    float* out = (float*)d_out;                  // (B, 1, L)

    const int grid = 64 * (LWORDS / WPB);        // 64 * 8 = 512 blocks, 1/CU
    score_max_kernel<<<grid, TPB, 0, stream>>>(in0, in1, out);
}

// Round 8
// 144.209 us; speedup vs baseline: 18.7917x; 18.7917x over previous
//
#include <hip/hip_runtime.h>
#include <math.h>

// Problem: B=64, R=20, L=1024, D=2048 fp32.  out[b,l] = max_r <region[b,r,:], word[b,l,:]>
// Memory-bound: 548 MB mandatory -> ~84us @ 6.6TB/s measured-achievable.
//
// Round-8 = round-5 shape + vmcnt ORDER fix:
//  - 4 waves/block (256 thr), each wave owns 4 words and ALL 20 regions
//    (word bytes read exactly once from HBM). 2 x 20KB LDS double buffer,
//    4 blocks/CU, 16 waves/CU.
//  - Per chunk: ONE barrier, then issue the 4 word loads FIRST, then the 5
//    async stage loads for chunk c+1. vmcnt is in-order, so the FMA's wait
//    on the words is vmcnt(5) and the stage stays in flight under the
//    ~640-cycle FMA phase (round 5 had stage-first -> every chunk drained
//    the stage serially).
//  - words are named float4 scalars (round 7: pointer-passed local arrays
//    went to scratch -> 1.3 GB spill traffic).
//  - no min-waves launch bound (rounds 3/4: VGPR caps spill the 80-reg acc).
#define NREG  20
#define LWORDS 1024
#define DDIM  2048
#define DK    256                   // D-chunk: 20*256*4B = 20 KB per buffer
#define NCHUNK (DDIM / DK)          // 8
#define NWAVE 4
#define TPB   (NWAVE * 64)          // 256
#define WPW   4                     // words per wave
#define WORDS_PER_BLOCK (NWAVE * WPW)   // 16

// async global->LDS, 16B per lane; dst must be wave-uniform (HW adds lane*16)
__device__ __forceinline__ void gload_lds16(const float* src, float* dst) {
    __builtin_amdgcn_global_load_lds(
        (const __attribute__((address_space(1))) void*)src,
        (__attribute__((address_space(3))) void*)dst,
        16, 0, 0);
}

// DPP full-wave (64-lane) sum; result valid in lane 63.
template <int CTRL>
__device__ __forceinline__ float dpp_add_f32(float v) {
    int s = __builtin_amdgcn_update_dpp(0, __float_as_int(v), CTRL, 0xf, 0xf, true);
    return v + __int_as_float(s);
}
__device__ __forceinline__ float wave_sum64(float v) {
    v = dpp_add_f32<0x111>(v);  // row_shr:1
    v = dpp_add_f32<0x112>(v);  // row_shr:2
    v = dpp_add_f32<0x114>(v);  // row_shr:4
    v = dpp_add_f32<0x118>(v);  // row_shr:8
    v = dpp_add_f32<0x142>(v);  // row_bcast:15
    v = dpp_add_f32<0x143>(v);  // row_bcast:31 -> lane 63 = total
    return v;
}

__global__ __launch_bounds__(TPB)
void score_max_kernel(const float* __restrict__ in0,   // (B*20, D) regions
                      const float* __restrict__ in1,   // (B, L, D) words
                      float* __restrict__ out) {       // (B, 1, L)
    __shared__ float reg_lds[2][NREG * DK];            // 40 KB double buffer

    const int bid  = blockIdx.x;
    // bid = t*64 + b: batch b always lands on XCD (b%8) -> regions L2-resident.
    const int b    = bid & 63;
    const int t    = bid >> 6;
    const int tid  = threadIdx.x;
    const int wave = tid >> 6;
    const int lane = tid & 63;
    const int l0   = t * WORDS_PER_BLOCK + wave * WPW;

    const float* regbase = in0 + (size_t)b * NREG * DDIM;
    const float* wordp   = in1 + ((size_t)b * LWORDS + l0) * DDIM + lane * 4;

    // stage regions[0..19][c*DK .. +DK) into reg_lds[bufsel] (async, 5 rows/wave)
    auto stage = [&](int bufsel, int c) {
        #pragma unroll
        for (int i = 0; i < NREG / NWAVE; ++i) {        // 5 rows per wave
            const int r = i * NWAVE + wave;              // wave-uniform row
            gload_lds16(regbase + (size_t)r * DDIM + c * DK + lane * 4,
                        &reg_lds[bufsel][r * DK]);
        }
    };

    float acc[NREG][WPW];
    #pragma unroll
    for (int r = 0; r < NREG; ++r)
        #pragma unroll
        for (int w = 0; w < WPW; ++w) acc[r][w] = 0.0f;

    stage(0, 0);
    int buf = 0;
    for (int c = 0; c < NCHUNK; ++c) {
        // barrier: drains stage(c) (issued last chunk, completed under FMAs)
        // and guarantees all waves finished reading reg_lds[buf^1].
        __syncthreads();

        // ---- word loads FIRST: oldest in the vmcnt queue ----
        const float* wp = wordp + c * DK;
        const float4 wv0 = *reinterpret_cast<const float4*>(wp);
        const float4 wv1 = *reinterpret_cast<const float4*>(wp + DDIM);
        const float4 wv2 = *reinterpret_cast<const float4*>(wp + 2 * (size_t)DDIM);
        const float4 wv3 = *reinterpret_cast<const float4*>(wp + 3 * (size_t)DDIM);
        __builtin_amdgcn_sched_barrier(0);   // pin: stage must issue AFTER words

        if (c + 1 < NCHUNK) stage(buf ^ 1, c + 1);   // stays in flight under FMAs

        const float* rbase = &reg_lds[buf][lane * 4];
        #pragma unroll
        for (int r = 0; r < NREG; ++r) {
            const float4 rv = *reinterpret_cast<const float4*>(rbase + r * DK);
            float a0 = acc[r][0], a1 = acc[r][1], a2 = acc[r][2], a3 = acc[r][3];
            a0 = fmaf(rv.x, wv0.x, a0); a1 = fmaf(rv.x, wv1.x, a1);
            a2 = fmaf(rv.x, wv2.x, a2); a3 = fmaf(rv.x, wv3.x, a3);
            a0 = fmaf(rv.y, wv0.y, a0); a1 = fmaf(rv.y, wv1.y, a1);
            a2 = fmaf(rv.y, wv2.y, a2); a3 = fmaf(rv.y, wv3.y, a3);
            a0 = fmaf(rv.z, wv0.z, a0); a1 = fmaf(rv.z, wv1.z, a1);
            a2 = fmaf(rv.z, wv2.z, a2); a3 = fmaf(rv.z, wv3.z, a3);
            a0 = fmaf(rv.w, wv0.w, a0); a1 = fmaf(rv.w, wv1.w, a1);
            a2 = fmaf(rv.w, wv2.w, a2); a3 = fmaf(rv.w, wv3.w, a3);
            acc[r][0] = a0; acc[r][1] = a1; acc[r][2] = a2; acc[r][3] = a3;
        }
        buf ^= 1;
    }

    // epilogue: DPP wave-sum each acc, max over regions, lane 63 stores.
    #pragma unroll
    for (int w = 0; w < WPW; ++w) {
        float m = -INFINITY;
        #pragma unroll
        for (int r = 0; r < NREG; ++r)
            m = fmaxf(m, wave_sum64(acc[r][w]));
        if (lane == 63) out[(size_t)b * LWORDS + l0 + w] = m;
    }
}

extern "C" void kernel_launch(void* const* d_in, const int* in_sizes, int n_in,
                              void* d_out, int out_size, void* d_ws, size_t ws_size,
                              hipStream_t stream) {
    const float* in0 = (const float*)d_in[0];   // (B*20, D)
    const float* in1 = (const float*)d_in[1];   // (B, L, D)
    float* out = (float*)d_out;                  // (B, 1, L)

    const int grid = 64 * (LWORDS / WORDS_PER_BLOCK);   // 64 * 64 = 4096
    score_max_kernel<<<grid, TPB, 0, stream>>>(in0, in1, out);
}